// Round 2
// baseline (13927.991 us; speedup 1.0000x reference)
//
#include <hip/hip_runtime.h>
#include <hip/hip_bf16.h>

// LSTM B=32,T=512,D=512,H=1024. Persistent-kernel design:
//  - one kernel runs all 512 timesteps; grid barrier via agent-scope atomics
//  - 64 blocks x 1024 threads (16 waves = 4 gates x 4 K-slices), co-resident
//  - Wt (bf16) held in registers (12 x bf16x8 per lane); zero in-loop W traffic
//  - A = [h | x_t] kept as hi/lo bf16 pair; z = (Ahi + Alo) @ bf16(W), fp32 acc
//  - c-state in epilogue-thread registers; h hi/lo ping-pong in global ws

#define B_   32
#define T_   512
#define D_   512
#define H_   1024
#define KTOT 1536
#define N4H  4096
#define NBLK 64

typedef __bf16 bf16_t;
typedef __bf16 bf16x8 __attribute__((ext_vector_type(8)));
typedef __bf16 bf16x4 __attribute__((ext_vector_type(4)));
typedef float f32x4 __attribute__((ext_vector_type(4)));

// ---------------------------------------------------------------------------
// Weight transpose to Wt[n][k] (k contiguous), combined rows k<1024 -> Wh,
// k>=1024 -> Wx. bf16 (hi only).
__global__ void wconv_kernel(const float* __restrict__ Wx,
                             const float* __restrict__ Wh,
                             bf16_t* __restrict__ WtHi) {
    __shared__ float tile[32][33];
    int k0 = blockIdx.x * 32;   // 48
    int n0 = blockIdx.y * 32;   // 128
    int tx = threadIdx.x;       // 0..31
    int ty = threadIdx.y;       // 0..7
    for (int i = ty; i < 32; i += 8) {
        int k = k0 + i;
        float v = (k < H_) ? Wh[(size_t)k * N4H + n0 + tx]
                           : Wx[(size_t)(k - H_) * N4H + n0 + tx];
        tile[i][tx] = v;
    }
    __syncthreads();
    for (int i = ty; i < 32; i += 8) {
        int n = n0 + i;
        WtHi[(size_t)n * KTOT + k0 + tx] = (bf16_t)tile[tx][i];
    }
}

// ---------------------------------------------------------------------------
// Input hi/lo bf16 split, float4-vectorized. Grid 8192 x 256 covers B*T*D/4.
__global__ void xconv_kernel(const float4* __restrict__ X,
                             bf16_t* __restrict__ XHi,
                             bf16_t* __restrict__ XLo) {
    int i = blockIdx.x * blockDim.x + threadIdx.x;
    float4 v = X[i];
    float arr[4] = {v.x, v.y, v.z, v.w};
    bf16x4 hi, lo;
#pragma unroll
    for (int j = 0; j < 4; ++j) {
        bf16_t h = (bf16_t)arr[j];
        hi[j] = h;
        lo[j] = (bf16_t)(arr[j] - (float)h);
    }
    *(bf16x4*)(XHi + 4 * (size_t)i) = hi;
    *(bf16x4*)(XLo + 4 * (size_t)i) = lo;
}

// ---------------------------------------------------------------------------
// Persistent LSTM kernel. Block b owns h-columns [16b,16b+16) for all gates.
// Wave w: gate g=w&3, K-slice s=w>>2 covering k in [384s, 384s+384).
// hbuf layout: [p][ hi: B_*H_ | lo: B_*H_ ] bf16, p = ping/pong.
__global__ __launch_bounds__(1024, 4) void lstm_kernel(
    const bf16_t* __restrict__ WtHi,
    const bf16_t* __restrict__ XHi, const bf16_t* __restrict__ XLo,
    bf16_t* __restrict__ hbuf,
    const float* __restrict__ bias,
    const int* __restrict__ seqlen,
    float* __restrict__ out,
    unsigned int* __restrict__ cnt) {
    __shared__ float zpart[4][4][32][16];  // [s][g][batch][col] 32 KB

    const int tid  = threadIdx.x;
    const int wave = tid >> 6;
    const int lane = tid & 63;
    const int quad = lane >> 4;
    const int lcol = lane & 15;
    const int g    = wave & 3;
    const int s    = wave >> 2;
    const int hc0  = blockIdx.x * 16;
    const int BH   = B_ * H_;

    // Load this wave's weight fragments into registers (once).
    bf16x8 wreg[12];
    {
        const int nz = g * H_ + hc0 + lcol;
        const bf16_t* wrow = WtHi + (size_t)nz * KTOT + s * 384 + quad * 8;
#pragma unroll
        for (int it = 0; it < 12; ++it)
            wreg[it] = *(const bf16x8*)(wrow + it * 32);
    }

    // Per-lane A-offset bases (m = lcol for tile0, lcol+16 for tile1).
    const int kq = s * 384 + quad * 8;  // wave/quad K base
    const int hb0 = lcol * H_;
    const int hb1 = (lcol + 16) * H_;
    const int xb0 = lcol * (T_ * D_);
    const int xb1 = (lcol + 16) * (T_ * D_);

    // Epilogue state: threads 0..511, one (batch,col) element each.
    const int eb = tid >> 4, ec = tid & 15;
    const int col = hc0 + ec;
    float creg = 0.f;
    float b0 = 0.f, b1 = 0.f, b2 = 0.f, b3 = 0.f;
    int slm1 = -1;
    if (tid < 512) {
        b0 = bias[col];
        b1 = bias[H_ + col];
        b2 = bias[2 * H_ + col];
        b3 = bias[3 * H_ + col];
        slm1 = seqlen[eb] - 1;
    }

#pragma unroll 1
    for (int t = 0; t < T_; ++t) {
        const bf16_t* hr = hbuf + (size_t)(t & 1) * 2 * BH;        // read
        bf16_t*       hw = hbuf + (size_t)((t + 1) & 1) * 2 * BH;  // write
        const bf16_t* xH = XHi + t * D_;
        const bf16_t* xL = XLo + t * D_;

        f32x4 acc0 = {0.f, 0.f, 0.f, 0.f};
        f32x4 acc1 = {0.f, 0.f, 0.f, 0.f};
#pragma unroll
        for (int it = 0; it < 12; ++it) {
            int k = kq + it * 32;
            const bf16_t *p0h, *p0l, *p1h, *p1l;
            if (k < H_) {
                p0h = hr + hb0 + k;        p0l = hr + BH + hb0 + k;
                p1h = hr + hb1 + k;        p1l = hr + BH + hb1 + k;
            } else {
                int kx = k - H_;
                p0h = xH + xb0 + kx;       p0l = xL + xb0 + kx;
                p1h = xH + xb1 + kx;       p1l = xL + xb1 + kx;
            }
            bf16x8 a0h = *(const bf16x8*)p0h;
            bf16x8 a0l = *(const bf16x8*)p0l;
            bf16x8 a1h = *(const bf16x8*)p1h;
            bf16x8 a1l = *(const bf16x8*)p1l;
            bf16x8 w = wreg[it];
            acc0 = __builtin_amdgcn_mfma_f32_16x16x32_bf16(a0h, w, acc0, 0, 0, 0);
            acc0 = __builtin_amdgcn_mfma_f32_16x16x32_bf16(a0l, w, acc0, 0, 0, 0);
            acc1 = __builtin_amdgcn_mfma_f32_16x16x32_bf16(a1h, w, acc1, 0, 0, 0);
            acc1 = __builtin_amdgcn_mfma_f32_16x16x32_bf16(a1l, w, acc1, 0, 0, 0);
        }
#pragma unroll
        for (int r = 0; r < 4; ++r) {
            zpart[s][g][quad * 4 + r][lcol]      = acc0[r];
            zpart[s][g][16 + quad * 4 + r][lcol] = acc1[r];
        }
        __syncthreads();

        if (tid < 512) {
            float zi = b0, zf = b1, zg = b2, zo = b3;
#pragma unroll
            for (int ss = 0; ss < 4; ++ss) {
                zi += zpart[ss][0][eb][ec];
                zf += zpart[ss][1][eb][ec];
                zg += zpart[ss][2][eb][ec];
                zo += zpart[ss][3][eb][ec];
            }
            float ig = 1.f / (1.f + __expf(-zi));
            float fg = 1.f / (1.f + __expf(-zf));
            float og = 1.f / (1.f + __expf(-zo));
            float gg = 1.f - 2.f / (__expf(2.f * zg) + 1.f);
            creg = fg * creg + ig * gg;
            float hn = og * (1.f - 2.f / (__expf(2.f * creg) + 1.f));
            bf16_t hh = (bf16_t)hn;
            hw[eb * H_ + col]      = hh;
            hw[BH + eb * H_ + col] = (bf16_t)(hn - (float)hh);
            if (slm1 == t) out[eb * H_ + col] = hn;
        }

        // Grid barrier: all blocks must finish step t before any starts t+1.
        __syncthreads();  // drains each wave's vmem stores before s_barrier
        if (tid == 0) {
            __threadfence();  // release: push h stores past non-coherent L2
            __hip_atomic_fetch_add(cnt, 1u, __ATOMIC_RELAXED,
                                   __HIP_MEMORY_SCOPE_AGENT);
            unsigned tgt = (unsigned)(t + 1) * NBLK;
            while (__hip_atomic_load(cnt, __ATOMIC_RELAXED,
                                     __HIP_MEMORY_SCOPE_AGENT) < tgt) {
            }
            __threadfence();  // acquire: invalidate stale L1/L2 lines
        }
        __syncthreads();
    }
}

// ---------------------------------------------------------------------------
extern "C" void kernel_launch(void* const* d_in, const int* in_sizes, int n_in,
                              void* d_out, int out_size, void* d_ws, size_t ws_size,
                              hipStream_t stream) {
    const float* inputs = (const float*)d_in[0];
    const int*   seqlen = (const int*)d_in[1];
    const float* Wx     = (const float*)d_in[2];
    const float* Wh     = (const float*)d_in[3];
    const float* bias   = (const float*)d_in[4];
    float* out = (float*)d_out;

    char* ws = (char*)d_ws;
    size_t o = 0;
    bf16_t* WtHi = (bf16_t*)(ws + o); o += (size_t)N4H * KTOT * 2;   // 12.6 MB
    bf16_t* XHi  = (bf16_t*)(ws + o); o += (size_t)B_ * T_ * D_ * 2; // 16.8 MB
    bf16_t* XLo  = (bf16_t*)(ws + o); o += (size_t)B_ * T_ * D_ * 2; // 16.8 MB
    bf16_t* hbuf = (bf16_t*)(ws + o); o += (size_t)4 * B_ * H_ * 2;  // 256 KB
    unsigned int* cnt = (unsigned int*)(ws + o); o += 256;

    wconv_kernel<<<dim3(48, 128), dim3(32, 8), 0, stream>>>(Wx, Wh, WtHi);
    xconv_kernel<<<(B_ * T_ * D_ / 4) / 256, 256, 0, stream>>>(
        (const float4*)inputs, XHi, XLo);
    // zero h ping buffer (hi+lo of p=0) and the barrier counter
    hipMemsetAsync(hbuf, 0, (size_t)2 * B_ * H_ * 2, stream);
    hipMemsetAsync(cnt, 0, sizeof(unsigned int), stream);

    lstm_kernel<<<NBLK, 1024, 0, stream>>>(WtHi, XHi, XLo, hbuf, bias, seqlen,
                                           out, cnt);
}

// Round 3
// 5802.802 us; speedup vs baseline: 2.4002x; 2.4002x over previous
//
#include <hip/hip_runtime.h>
#include <hip/hip_bf16.h>

// LSTM B=32,T=512,D=512,H=1024, persistent kernel, NO cache-flushing fences.
//  - h crosses XCDs via device-scope RELAXED atomics (sc1, L2-bypass, served
//    at coherence point). No __threadfence -> no buffer_wbl2/buffer_inv ->
//    X and W stay L2-resident.
//  - grid barrier: monotonic counter; ordering via the s_waitcnt vmcnt(0)
//    the compiler emits before s_barrier (all h-stores drained before add).
//  - 64 blocks x 512 thr (8 waves = 8 K-slices x all 4 gates): zero redundant
//    A-reads. W (bf16) in 24 bf16x8 regs/lane. h,x packed (hi|lo<<16) uint32.

#define B_   32
#define T_   512
#define D_   512
#define H_   1024
#define KTOT 1536
#define N4H  4096
#define NBLK 64

typedef __bf16 bf16_t;
typedef __bf16 bf16x8 __attribute__((ext_vector_type(8)));
typedef float f32x4 __attribute__((ext_vector_type(4)));

// ---------------------------------------------------------------------------
__global__ void wconv_kernel(const float* __restrict__ Wx,
                             const float* __restrict__ Wh,
                             bf16_t* __restrict__ Wt) {
    __shared__ float tile[32][33];
    int k0 = blockIdx.x * 32;
    int n0 = blockIdx.y * 32;
    int tx = threadIdx.x;
    int ty = threadIdx.y;
    for (int i = ty; i < 32; i += 8) {
        int k = k0 + i;
        float v = (k < H_) ? Wh[(size_t)k * N4H + n0 + tx]
                           : Wx[(size_t)(k - H_) * N4H + n0 + tx];
        tile[i][tx] = v;
    }
    __syncthreads();
    for (int i = ty; i < 32; i += 8)
        Wt[(size_t)(n0 + i) * KTOT + k0 + tx] = (bf16_t)tile[tx][i];
}

// ---------------------------------------------------------------------------
// X -> packed uint32 per element: low16 = bf16(hi), high16 = bf16(residual).
__global__ void xconv_kernel(const float4* __restrict__ X,
                             uint4* __restrict__ Xpk) {
    int i = blockIdx.x * blockDim.x + threadIdx.x;
    float4 v = X[i];
    float arr[4] = {v.x, v.y, v.z, v.w};
    unsigned pk[4];
#pragma unroll
    for (int j = 0; j < 4; ++j) {
        bf16_t h = (bf16_t)arr[j];
        bf16_t l = (bf16_t)(arr[j] - (float)h);
        pk[j] = (unsigned)__builtin_bit_cast(unsigned short, h) |
                ((unsigned)__builtin_bit_cast(unsigned short, l) << 16);
    }
    Xpk[i] = make_uint4(pk[0], pk[1], pk[2], pk[3]);
}

// ---------------------------------------------------------------------------
__device__ __forceinline__ void unpack16(const unsigned short* s,
                                         bf16x8* hi, bf16x8* lo) {
#pragma unroll
    for (int j = 0; j < 8; ++j) {
        (*hi)[j] = __builtin_bit_cast(bf16_t, s[2 * j]);
        (*lo)[j] = __builtin_bit_cast(bf16_t, s[2 * j + 1]);
    }
}

// h fragment: 8 packed uints via 4 device-scope relaxed 8B atomic loads (sc1).
__device__ __forceinline__ void load_h_frag(const unsigned* p,
                                            bf16x8* hi, bf16x8* lo) {
    union { unsigned long long u[4]; unsigned short s[16]; } v;
    const unsigned long long* q = (const unsigned long long*)p;
#pragma unroll
    for (int j = 0; j < 4; ++j)
        v.u[j] = __hip_atomic_load(q + j, __ATOMIC_RELAXED,
                                   __HIP_MEMORY_SCOPE_AGENT);
    unpack16(v.s, hi, lo);
}

// x fragment: normal cacheable 2x dwordx4.
__device__ __forceinline__ void load_x_frag(const unsigned* p,
                                            bf16x8* hi, bf16x8* lo) {
    union { uint4 q[2]; unsigned short s[16]; } v;
    v.q[0] = *(const uint4*)p;
    v.q[1] = *(const uint4*)(p + 4);
    unpack16(v.s, hi, lo);
}

// ---------------------------------------------------------------------------
// Block b owns h-cols [16b,16b+16). Wave w = K-slice [192w,192w+192), all 4
// gates. hpk: ping-pong packed h, accessed ONLY via device-scope atomics.
__global__ __launch_bounds__(512, 2) void lstm_kernel(
    const bf16_t* __restrict__ Wt,
    const unsigned* __restrict__ Xpk,
    unsigned* __restrict__ hpk,
    const float* __restrict__ bias,
    const int* __restrict__ seqlen,
    float* __restrict__ out,
    unsigned* __restrict__ cnt) {
    __shared__ float zpart[8][4][32][16];  // 64 KB: [slice][gate][batch][col]

    const int tid  = threadIdx.x;
    const int w    = tid >> 6;
    const int lane = tid & 63;
    const int quad = lane >> 4;
    const int lcol = lane & 15;
    const int hc0  = blockIdx.x * 16;
    const int BH   = B_ * H_;

    // Weight fragments: 4 gates x 6 k-iters, once.
    bf16x8 wreg[24];
#pragma unroll
    for (int g = 0; g < 4; ++g)
#pragma unroll
        for (int it = 0; it < 6; ++it)
            wreg[g * 6 + it] = *(const bf16x8*)(
                Wt + (size_t)(g * H_ + hc0 + lcol) * KTOT + w * 192 + it * 32 +
                quad * 8);

    // Epilogue: 512 threads = one (batch,col) element each.
    const int eb = tid >> 4, ec = tid & 15;
    const int col = hc0 + ec;
    float creg = 0.f;
    const float b0 = bias[col];
    const float b1 = bias[H_ + col];
    const float b2 = bias[2 * H_ + col];
    const float b3 = bias[3 * H_ + col];
    const int slm1 = seqlen[eb] - 1;

#pragma unroll 1
    for (int t = 0; t < T_; ++t) {
        const unsigned* hr = hpk + (size_t)(t & 1) * BH;
        unsigned*       hw = hpk + (size_t)((t + 1) & 1) * BH;

        f32x4 acc[8];
#pragma unroll
        for (int i = 0; i < 8; ++i) acc[i] = (f32x4){0.f, 0.f, 0.f, 0.f};

#pragma unroll
        for (int it = 0; it < 6; ++it) {
            int k  = w * 192 + it * 32;
            int kq = k + quad * 8;
            bf16x8 a0h, a0l, a1h, a1l;
            if (k < H_) {
                load_h_frag(hr + lcol * H_ + kq, &a0h, &a0l);
                load_h_frag(hr + (lcol + 16) * H_ + kq, &a1h, &a1l);
            } else {
                int kx = kq - H_;
                load_x_frag(Xpk + ((size_t)lcol * T_ + t) * D_ + kx, &a0h, &a0l);
                load_x_frag(Xpk + ((size_t)(lcol + 16) * T_ + t) * D_ + kx,
                            &a1h, &a1l);
            }
#pragma unroll
            for (int g = 0; g < 4; ++g) {
                bf16x8 wv = wreg[g * 6 + it];
                acc[g * 2] = __builtin_amdgcn_mfma_f32_16x16x32_bf16(
                    a0h, wv, acc[g * 2], 0, 0, 0);
                acc[g * 2] = __builtin_amdgcn_mfma_f32_16x16x32_bf16(
                    a0l, wv, acc[g * 2], 0, 0, 0);
                acc[g * 2 + 1] = __builtin_amdgcn_mfma_f32_16x16x32_bf16(
                    a1h, wv, acc[g * 2 + 1], 0, 0, 0);
                acc[g * 2 + 1] = __builtin_amdgcn_mfma_f32_16x16x32_bf16(
                    a1l, wv, acc[g * 2 + 1], 0, 0, 0);
            }
        }
#pragma unroll
        for (int g = 0; g < 4; ++g)
#pragma unroll
            for (int r = 0; r < 4; ++r) {
                zpart[w][g][quad * 4 + r][lcol]      = acc[g * 2][r];
                zpart[w][g][16 + quad * 4 + r][lcol] = acc[g * 2 + 1][r];
            }
        __syncthreads();

        // Epilogue (all 512 threads).
        float zi = b0, zf = b1, zg = b2, zo = b3;
#pragma unroll
        for (int ss = 0; ss < 8; ++ss) {
            zi += zpart[ss][0][eb][ec];
            zf += zpart[ss][1][eb][ec];
            zg += zpart[ss][2][eb][ec];
            zo += zpart[ss][3][eb][ec];
        }
        float ig = 1.f / (1.f + __expf(-zi));
        float fg = 1.f / (1.f + __expf(-zf));
        float og = 1.f / (1.f + __expf(-zo));
        float gg = 1.f - 2.f / (__expf(2.f * zg) + 1.f);
        creg = fg * creg + ig * gg;
        float hn = og * (1.f - 2.f / (__expf(2.f * creg) + 1.f));
        bf16_t hh = (bf16_t)hn;
        bf16_t hl = (bf16_t)(hn - (float)hh);
        unsigned pk = (unsigned)__builtin_bit_cast(unsigned short, hh) |
                      ((unsigned)__builtin_bit_cast(unsigned short, hl) << 16);
        __hip_atomic_store(hw + eb * H_ + col, pk, __ATOMIC_RELAXED,
                           __HIP_MEMORY_SCOPE_AGENT);
        if (slm1 == t) out[eb * H_ + col] = hn;

        // Barrier. __syncthreads drains each wave's vmem (compiler emits
        // s_waitcnt vmcnt(0) before s_barrier), so by the time tid 0 adds,
        // every wave's sc1 h-stores are at the coherence point. No fences.
        __syncthreads();
        if (tid == 0) {
            __hip_atomic_fetch_add(cnt, 1u, __ATOMIC_RELAXED,
                                   __HIP_MEMORY_SCOPE_AGENT);
            unsigned tgt = (unsigned)(t + 1) * NBLK;
            while (__hip_atomic_load(cnt, __ATOMIC_RELAXED,
                                     __HIP_MEMORY_SCOPE_AGENT) < tgt) {
            }
        }
        __syncthreads();
    }
}

// ---------------------------------------------------------------------------
extern "C" void kernel_launch(void* const* d_in, const int* in_sizes, int n_in,
                              void* d_out, int out_size, void* d_ws, size_t ws_size,
                              hipStream_t stream) {
    const float* inputs = (const float*)d_in[0];
    const int*   seqlen = (const int*)d_in[1];
    const float* Wx     = (const float*)d_in[2];
    const float* Wh     = (const float*)d_in[3];
    const float* bias   = (const float*)d_in[4];
    float* out = (float*)d_out;

    char* ws = (char*)d_ws;
    size_t o = 0;
    bf16_t*   Wt  = (bf16_t*)(ws + o);   o += (size_t)N4H * KTOT * 2;  // 12.6MB
    unsigned* Xpk = (unsigned*)(ws + o); o += (size_t)B_ * T_ * D_ * 4; // 33.6MB
    unsigned* hpk = (unsigned*)(ws + o); o += (size_t)2 * B_ * H_ * 4;  // 256KB
    unsigned* cnt = (unsigned*)(ws + o); o += 256;

    wconv_kernel<<<dim3(48, 128), dim3(32, 8), 0, stream>>>(Wx, Wh, Wt);
    xconv_kernel<<<(B_ * T_ * D_ / 4) / 256, 256, 0, stream>>>(
        (const float4*)inputs, (uint4*)Xpk);
    hipMemsetAsync(hpk, 0, (size_t)B_ * H_ * 4, stream);  // ping p=0
    hipMemsetAsync(cnt, 0, sizeof(unsigned), stream);

    lstm_kernel<<<NBLK, 512, 0, stream>>>(Wt, Xpk, hpk, bias, seqlen, out, cnt);
}

// Round 4
// 4192.186 us; speedup vs baseline: 3.3224x; 1.3842x over previous
//
#include <hip/hip_runtime.h>
#include <hip/hip_bf16.h>

// LSTM B=32,T=512,D=512,H=1024, persistent kernel.
// R4 changes vs R3:
//  - h stored in MFMA-fragment-major layout: uint index
//      (k>>5)*1024 + (b>>4)*512 + (((k>>3)&3)*16 + (b&15))*8 + (k&7)
//    so each wave's A-fragment load is 64 lanes x 32 B fully contiguous ->
//    8B sc1 atomic loads coalesce into full 64B lines (8x fewer fabric txns).
//  - h writes staged through LDS (overlaid on zpart) -> 256 contiguous 8B
//    sc1 stores per block.
//  - tree barrier: 8 groups x 8 blocks, 64B-padded counters, s_sleep backoff.

#define B_   32
#define T_   512
#define D_   512
#define H_   1024
#define KTOT 1536
#define N4H  4096
#define NBLK 64

typedef __bf16 bf16_t;
typedef __bf16 bf16x8 __attribute__((ext_vector_type(8)));
typedef float f32x4 __attribute__((ext_vector_type(4)));

// ---------------------------------------------------------------------------
__global__ void wconv_kernel(const float* __restrict__ Wx,
                             const float* __restrict__ Wh,
                             bf16_t* __restrict__ Wt) {
    __shared__ float tile[32][33];
    int k0 = blockIdx.x * 32;
    int n0 = blockIdx.y * 32;
    int tx = threadIdx.x;
    int ty = threadIdx.y;
    for (int i = ty; i < 32; i += 8) {
        int k = k0 + i;
        float v = (k < H_) ? Wh[(size_t)k * N4H + n0 + tx]
                           : Wx[(size_t)(k - H_) * N4H + n0 + tx];
        tile[i][tx] = v;
    }
    __syncthreads();
    for (int i = ty; i < 32; i += 8)
        Wt[(size_t)(n0 + i) * KTOT + k0 + tx] = (bf16_t)tile[tx][i];
}

// ---------------------------------------------------------------------------
// X -> packed uint32 per element: low16 = bf16(hi), high16 = bf16(residual).
__global__ void xconv_kernel(const float4* __restrict__ X,
                             uint4* __restrict__ Xpk) {
    int i = blockIdx.x * blockDim.x + threadIdx.x;
    float4 v = X[i];
    float arr[4] = {v.x, v.y, v.z, v.w};
    unsigned pk[4];
#pragma unroll
    for (int j = 0; j < 4; ++j) {
        bf16_t h = (bf16_t)arr[j];
        bf16_t l = (bf16_t)(arr[j] - (float)h);
        pk[j] = (unsigned)__builtin_bit_cast(unsigned short, h) |
                ((unsigned)__builtin_bit_cast(unsigned short, l) << 16);
    }
    Xpk[i] = make_uint4(pk[0], pk[1], pk[2], pk[3]);
}

// ---------------------------------------------------------------------------
__device__ __forceinline__ void unpack16(const unsigned short* s,
                                         bf16x8* hi, bf16x8* lo) {
#pragma unroll
    for (int j = 0; j < 8; ++j) {
        (*hi)[j] = __builtin_bit_cast(bf16_t, s[2 * j]);
        (*lo)[j] = __builtin_bit_cast(bf16_t, s[2 * j + 1]);
    }
}

// h fragment: 32 B contiguous per lane (frag-major layout), 4x 8B sc1 loads.
__device__ __forceinline__ void load_h_frag(const unsigned* p,
                                            bf16x8* hi, bf16x8* lo) {
    union { unsigned long long u[4]; unsigned short s[16]; } v;
    const unsigned long long* q = (const unsigned long long*)p;
#pragma unroll
    for (int j = 0; j < 4; ++j)
        v.u[j] = __hip_atomic_load(q + j, __ATOMIC_RELAXED,
                                   __HIP_MEMORY_SCOPE_AGENT);
    unpack16(v.s, hi, lo);
}

// x fragment: normal cacheable 2x dwordx4.
__device__ __forceinline__ void load_x_frag(const unsigned* p,
                                            bf16x8* hi, bf16x8* lo) {
    union { uint4 q[2]; unsigned short s[16]; } v;
    v.q[0] = *(const uint4*)p;
    v.q[1] = *(const uint4*)(p + 4);
    unpack16(v.s, hi, lo);
}

// ---------------------------------------------------------------------------
// Block b owns h-cols [16b,16b+16). Wave w = K-slice [192w,192w+192), all 4
// gates. hpk ping-pong, frag-major layout, accessed only via sc1 atomics.
__global__ __launch_bounds__(512, 2) void lstm_kernel(
    const bf16_t* __restrict__ Wt,
    const unsigned* __restrict__ Xpk,
    unsigned* __restrict__ hpk,
    const float* __restrict__ bias,
    const int* __restrict__ seqlen,
    float* __restrict__ out,
    unsigned* __restrict__ cnt) {
    __shared__ float zpart[8][4][32][16];  // 64 KB; tail reused as h-stage

    const int tid  = threadIdx.x;
    const int w    = tid >> 6;
    const int lane = tid & 63;
    const int quad = lane >> 4;
    const int lcol = lane & 15;
    const int hc0  = blockIdx.x * 16;
    const int HW_  = 32768;                // uints per h buffer (B_*H_)

    // Weight fragments: 4 gates x 6 k-iters, once.
    bf16x8 wreg[24];
#pragma unroll
    for (int g = 0; g < 4; ++g)
#pragma unroll
        for (int it = 0; it < 6; ++it)
            wreg[g * 6 + it] = *(const bf16x8*)(
                Wt + (size_t)(g * H_ + hc0 + lcol) * KTOT + w * 192 + it * 32 +
                quad * 8);

    // Epilogue mapping: 512 threads = one (batch,col) element each.
    const int eb = tid >> 4, ec = tid & 15;
    const int col = hc0 + ec;
    float creg = 0.f;
    const float b0 = bias[col];
    const float b1 = bias[H_ + col];
    const float b2 = bias[2 * H_ + col];
    const float b3 = bias[3 * H_ + col];
    const int slm1 = seqlen[eb] - 1;
    // LDS stage index (destination-ordered within this block's h region).
    const int stageIdx = (eb >> 4) * 256 + ((ec >> 3) * 16 + (eb & 15)) * 8 +
                         (ec & 7);
    // Store-phase constants.
    const int kbB  = (hc0 >> 5) * 1024;    // k-block base (uints)
    const int qlo  = (hc0 >> 4) & 1;       // which quad-pair within k-block
    const int dst0 = kbB + (tid >> 7) * 512 + qlo * 256 + (tid & 127) * 2;

#pragma unroll 1
    for (int t = 0; t < T_; ++t) {
        const unsigned* hr = hpk + (size_t)(t & 1) * HW_;
        unsigned*       hw = hpk + (size_t)((t + 1) & 1) * HW_;

        f32x4 acc[8];
#pragma unroll
        for (int i = 0; i < 8; ++i) acc[i] = (f32x4){0.f, 0.f, 0.f, 0.f};

#pragma unroll
        for (int it = 0; it < 6; ++it) {
            int kb = w * 6 + it;           // 32-wide k-block index
            bf16x8 a0h, a0l, a1h, a1l;
            if (kb < 32) {                 // h region: frag-major, coalesced
                const unsigned* fb = hr + kb * 1024 + lane * 8;
                load_h_frag(fb,       &a0h, &a0l);   // batches 0..15
                load_h_frag(fb + 512, &a1h, &a1l);   // batches 16..31
            } else {                       // x region: row-major cached
                int kx = kb * 32 - H_ + quad * 8;
                load_x_frag(Xpk + ((size_t)lcol * T_ + t) * D_ + kx, &a0h, &a0l);
                load_x_frag(Xpk + ((size_t)(lcol + 16) * T_ + t) * D_ + kx,
                            &a1h, &a1l);
            }
#pragma unroll
            for (int g = 0; g < 4; ++g) {
                bf16x8 wv = wreg[g * 6 + it];
                acc[g * 2] = __builtin_amdgcn_mfma_f32_16x16x32_bf16(
                    a0h, wv, acc[g * 2], 0, 0, 0);
                acc[g * 2] = __builtin_amdgcn_mfma_f32_16x16x32_bf16(
                    a0l, wv, acc[g * 2], 0, 0, 0);
                acc[g * 2 + 1] = __builtin_amdgcn_mfma_f32_16x16x32_bf16(
                    a1h, wv, acc[g * 2 + 1], 0, 0, 0);
                acc[g * 2 + 1] = __builtin_amdgcn_mfma_f32_16x16x32_bf16(
                    a1l, wv, acc[g * 2 + 1], 0, 0, 0);
            }
        }
#pragma unroll
        for (int g = 0; g < 4; ++g)
#pragma unroll
            for (int r = 0; r < 4; ++r) {
                zpart[w][g][quad * 4 + r][lcol]      = acc[g * 2][r];
                zpart[w][g][16 + quad * 4 + r][lcol] = acc[g * 2 + 1][r];
            }
        __syncthreads();  // A: zpart complete

        // Epilogue (all 512 threads).
        float zi = b0, zf = b1, zg = b2, zo = b3;
#pragma unroll
        for (int ss = 0; ss < 8; ++ss) {
            zi += zpart[ss][0][eb][ec];
            zf += zpart[ss][1][eb][ec];
            zg += zpart[ss][2][eb][ec];
            zo += zpart[ss][3][eb][ec];
        }
        float ig = 1.f / (1.f + __expf(-zi));
        float fg = 1.f / (1.f + __expf(-zf));
        float og = 1.f / (1.f + __expf(-zo));
        float gg = 1.f - 2.f / (__expf(2.f * zg) + 1.f);
        creg = fg * creg + ig * gg;
        float hn = og * (1.f - 2.f / (__expf(2.f * creg) + 1.f));
        bf16_t hh = (bf16_t)hn;
        bf16_t hl = (bf16_t)(hn - (float)hh);
        unsigned pk = (unsigned)__builtin_bit_cast(unsigned short, hh) |
                      ((unsigned)__builtin_bit_cast(unsigned short, hl) << 16);
        if (slm1 == t) out[eb * H_ + col] = hn;

        __syncthreads();  // B: everyone done reading zpart -> reuse as stage
        unsigned* stage = (unsigned*)&zpart[0][0][0][0];
        stage[stageIdx] = pk;
        __syncthreads();  // C: stage complete

        if (tid < 256) {
            unsigned long long val = ((const unsigned long long*)stage)[tid];
            __hip_atomic_store((unsigned long long*)(hw + dst0), val,
                               __ATOMIC_RELAXED, __HIP_MEMORY_SCOPE_AGENT);
        }

        // Drain stores, then tree barrier (8 groups x 8).
        asm volatile("s_waitcnt vmcnt(0)" ::: "memory");
        __syncthreads();  // D
        if (tid == 0) {
            int grp = blockIdx.x >> 3;
            unsigned old = __hip_atomic_fetch_add(
                cnt + 16 + grp * 16, 1u, __ATOMIC_RELAXED,
                __HIP_MEMORY_SCOPE_AGENT);
            if ((old & 7u) == 7u)
                __hip_atomic_fetch_add(cnt, 1u, __ATOMIC_RELAXED,
                                       __HIP_MEMORY_SCOPE_AGENT);
            unsigned tgt = (unsigned)(t + 1) * 8u;
            while (__hip_atomic_load(cnt, __ATOMIC_RELAXED,
                                     __HIP_MEMORY_SCOPE_AGENT) < tgt)
                __builtin_amdgcn_s_sleep(1);
            asm volatile("" ::: "memory");
        }
        __syncthreads();  // E: release
    }
}

// ---------------------------------------------------------------------------
extern "C" void kernel_launch(void* const* d_in, const int* in_sizes, int n_in,
                              void* d_out, int out_size, void* d_ws, size_t ws_size,
                              hipStream_t stream) {
    const float* inputs = (const float*)d_in[0];
    const int*   seqlen = (const int*)d_in[1];
    const float* Wx     = (const float*)d_in[2];
    const float* Wh     = (const float*)d_in[3];
    const float* bias   = (const float*)d_in[4];
    float* out = (float*)d_out;

    char* ws = (char*)d_ws;
    size_t o = 0;
    bf16_t*   Wt  = (bf16_t*)(ws + o);   o += (size_t)N4H * KTOT * 2;   // 12.6MB
    unsigned* Xpk = (unsigned*)(ws + o); o += (size_t)B_ * T_ * D_ * 4; // 33.6MB
    unsigned* hpk = (unsigned*)(ws + o); o += (size_t)2 * B_ * H_ * 4;  // 256KB
    unsigned* cnt = (unsigned*)(ws + o); o += 4096;

    wconv_kernel<<<dim3(48, 128), dim3(32, 8), 0, stream>>>(Wx, Wh, Wt);
    xconv_kernel<<<(B_ * T_ * D_ / 4) / 256, 256, 0, stream>>>(
        (const float4*)inputs, (uint4*)Xpk);
    hipMemsetAsync(hpk, 0, (size_t)B_ * H_ * 4, stream);  // ping p=0 zeros
    hipMemsetAsync(cnt, 0, 4096, stream);                 // barrier counters

    lstm_kernel<<<NBLK, 512, 0, stream>>>(Wt, Xpk, hpk, bias, seqlen, out, cnt);
}